// Round 7
// baseline (65.070 us; speedup 1.0000x reference)
//
#include <hip/hip_runtime.h>
#include <hip/hip_bf16.h>

typedef __bf16 bf16x8 __attribute__((ext_vector_type(8)));
typedef float f32x4 __attribute__((ext_vector_type(4)));

#define B_    8
#define NTOK  4096
#define CIN   512
#define COUT  512
#define SDIM  512
#define EPSF  1e-8f

// ---------------------------------------------------------------------------
// K1: m[b][i] = style[b,:] . mod_w[i,:] + mod_b[i] + 1    (one wave per output)
// ---------------------------------------------------------------------------
__global__ __launch_bounds__(256) void k_stylefc(
    const float* __restrict__ style, const float* __restrict__ mod_w,
    const float* __restrict__ mod_b, float* __restrict__ m_out) {
  int gw   = (blockIdx.x * 256 + threadIdx.x) >> 6;  // 0..4095
  int lane = threadIdx.x & 63;
  int b = gw >> 9;
  int i = gw & 511;
  const float* srow = style + (size_t)b * SDIM;
  const float* wrow = mod_w + (size_t)i * SDIM;
  float acc = 0.f;
#pragma unroll
  for (int k = 0; k < SDIM; k += 64) acc += srow[k + lane] * wrow[k + lane];
#pragma unroll
  for (int off = 32; off; off >>= 1) acc += __shfl_xor(acc, off, 64);
  if (lane == 0) m_out[b * CIN + i] = acc + mod_b[i] + 1.0f;
}

// ---------------------------------------------------------------------------
// K2 (fused): per output-channel o (one block each):
//  - demod[b][o] = rsqrt( sum_k (weight[k][o]*m[b][k])^2 + eps ),  8 b
//  - wimg: pre-swizzled bf16 W image, exact byte image of the GEMM's
//    fully-resident LDS W block.  Layout: [nb(4)][kt(16)][row(128)][64B]:
//      byte = nb*131072 + kt*8192 + row*64 + slot*16 + (k&7)*2
//      slot = ((k&31)>>3) ^ ((row>>1)&3),  row = o&127, nb = o>>7
//    (per-kt tile layout identical to R5's measured-0-conflict pattern)
// ---------------------------------------------------------------------------
__global__ __launch_bounds__(256) void k_wprep(
    const float* __restrict__ weight, const float* __restrict__ m_buf,
    __bf16* __restrict__ wimg, float* __restrict__ demod) {
  int o = blockIdx.x;
  int tid = threadIdx.x;
  int wid = tid >> 6, lane = tid & 63;
  int nb = o >> 7, row = o & 127;
  float acc[B_] = {0.f, 0.f, 0.f, 0.f, 0.f, 0.f, 0.f, 0.f};
#pragma unroll
  for (int rep = 0; rep < 2; ++rep) {
    int k = tid + rep * 256;
    float w = weight[(size_t)k * COUT + o];
    int kt = k >> 5, kl = k & 31, s = kl >> 3, ko = kl & 7;
    int sl = s ^ ((row >> 1) & 3);
    *(__bf16*)((char*)wimg + (size_t)nb * 131072 + kt * 8192 + row * 64 +
               sl * 16 + ko * 2) = (__bf16)w;
#pragma unroll
    for (int b = 0; b < B_; ++b) {
      float wm = w * m_buf[b * CIN + k];
      acc[b] += wm * wm;
    }
  }
  __shared__ float red[4][B_];
#pragma unroll
  for (int b = 0; b < B_; ++b) {
    float v = acc[b];
#pragma unroll
    for (int off = 32; off; off >>= 1) v += __shfl_xor(v, off, 64);
    if (lane == 0) red[wid][b] = v;
  }
  __syncthreads();
  if (tid < B_) {
    float s = red[0][tid] + red[1][tid] + red[2][tid] + red[3][tid];
    demod[tid * COUT + o] = rsqrtf(s + EPSF);
  }
}

// ---------------------------------------------------------------------------
// async global->LDS: dest = wave-uniform LDS base (+lane*16 by HW), src per-lane
// ---------------------------------------------------------------------------
__device__ __forceinline__ void async_copy16(void* lds_dst, const void* gsrc) {
  __builtin_amdgcn_global_load_lds(
      (const __attribute__((address_space(1))) unsigned int*)gsrc,
      (__attribute__((address_space(3))) unsigned int*)lds_dst, 16, 0, 0);
}

// ---------------------------------------------------------------------------
// K3: out[b,t,o] = demod[b][o] * sum_k (x[b,t,k]*m[b][k]) * W[k][o]
// BARRIER-FREE steady state.  256 blocks (1/CU) x 1024 thr (16 waves).
// Block tile: 512 tok x 128 o.  Wave-tile: 32 tok x 128 o, acc[8][2].
// W: 128 KB dynamic LDS, whole K resident, loaded ONCE via global_load_lds
//    behind a single prologue barrier.  Per-kt tile = R5's 0-conflict layout.
// X: global->reg, 1-deep prefetch (issue kt+1 at top of kt), *m, bf16 cvt.
//    4 nb-blocks of one x-panel on the same XCD -> x re-reads are L2 hits.
// ---------------------------------------------------------------------------
__global__ __launch_bounds__(1024) void k_gemm(
    const float* __restrict__ x, const __bf16* __restrict__ wimg,
    const float* __restrict__ m_buf, const float* __restrict__ demod,
    float* __restrict__ out) {
  // 256 blocks = 8 xcd * 32; panel (b,tb) = xcd*8 + (g>>2), nb = g&3
  int bid = blockIdx.x;
  int xcd = bid & 7;
  int g   = bid >> 3;                  // 0..31
  int panel = xcd * 8 + (g >> 2);      // 0..63
  int nb  = g & 3;
  int b   = panel >> 3, tb = panel & 7;

  extern __shared__ char ldsbuf[];     // 128 KB: [kt(16)][row(128)][64B]

  int tid = threadIdx.x;
  int wid = tid >> 6, lane = tid & 63;
  int ln15 = lane & 15, s = lane >> 4;

  const float* xb   = x + (size_t)(b * NTOK + tb * 512) * CIN;
  const float* mrow = m_buf + b * CIN;
  const char*  wsrc = (const char*)wimg + (size_t)nb * 131072;

  // ---- prologue: W -> LDS (once), X kt=0 -> regs (overlapped) ----
#pragma unroll
  for (int q = 0; q < 8; ++q) {
    int off = (q * 16 + wid) * 1024;
    async_copy16(ldsbuf + off, wsrc + off + lane * 16);
  }

  const float* xrow0 = xb + (size_t)(wid * 32 + ln15) * CIN + s * 8;
  const float* xrow1 = xrow0 + 16 * CIN;

  float4 xr[2][2][2];  // [buf][nn][half]
  float4 mvr[2][2];    // [buf][half]
  {
    const float* mp = mrow + s * 8;
    mvr[0][0] = *(const float4*)mp;
    mvr[0][1] = *(const float4*)(mp + 4);
    xr[0][0][0] = *(const float4*)xrow0;
    xr[0][0][1] = *(const float4*)(xrow0 + 4);
    xr[0][1][0] = *(const float4*)xrow1;
    xr[0][1][1] = *(const float4*)(xrow1 + 4);
  }
  __syncthreads();  // W resident; only barrier in the kernel

  f32x4 acc[8][2] = {};  // [mm: o-frag][nn: token-frag]

#pragma unroll
  for (int kt = 0; kt < 16; ++kt) {
    const int cur = kt & 1, nxt = cur ^ 1;
    if (kt < 15) {  // prefetch kt+1 (constant-folded under unroll)
      const float* mp = mrow + (kt + 1) * 32 + s * 8;
      mvr[nxt][0] = *(const float4*)mp;
      mvr[nxt][1] = *(const float4*)(mp + 4);
      const float* p0 = xrow0 + (kt + 1) * 32;
      const float* p1 = xrow1 + (kt + 1) * 32;
      xr[nxt][0][0] = *(const float4*)p0;
      xr[nxt][0][1] = *(const float4*)(p0 + 4);
      xr[nxt][1][0] = *(const float4*)p1;
      xr[nxt][1][1] = *(const float4*)(p1 + 4);
    }
    // W fragments for this kt (LDS, swizzled slot -> 0-conflict)
    bf16x8 wf[8];
#pragma unroll
    for (int mm = 0; mm < 8; ++mm) {
      int r = mm * 16 + ln15;
      wf[mm] = *(const bf16x8*)(ldsbuf + kt * 8192 + r * 64 +
                                ((s ^ ((r >> 1) & 3)) << 4));
    }
    // X fragments (regs) + MFMA
#pragma unroll
    for (int nn = 0; nn < 2; ++nn) {
      bf16x8 xf;
      xf[0] = (__bf16)(xr[cur][nn][0].x * mvr[cur][0].x);
      xf[1] = (__bf16)(xr[cur][nn][0].y * mvr[cur][0].y);
      xf[2] = (__bf16)(xr[cur][nn][0].z * mvr[cur][0].z);
      xf[3] = (__bf16)(xr[cur][nn][0].w * mvr[cur][0].w);
      xf[4] = (__bf16)(xr[cur][nn][1].x * mvr[cur][1].x);
      xf[5] = (__bf16)(xr[cur][nn][1].y * mvr[cur][1].y);
      xf[6] = (__bf16)(xr[cur][nn][1].z * mvr[cur][1].z);
      xf[7] = (__bf16)(xr[cur][nn][1].w * mvr[cur][1].w);
#pragma unroll
      for (int mm = 0; mm < 8; ++mm)
        acc[mm][nn] = __builtin_amdgcn_mfma_f32_16x16x32_bf16(
            wf[mm], xf, acc[mm][nn], 0, 0, 0);
    }
  }

  // ---- epilogue: out[t][o..o+3] = acc * demod, float4 stores ----
  float* ob = out + (size_t)(b * NTOK + tb * 512) * COUT + nb * 128;
  const float* dr = demod + b * COUT + nb * 128;
#pragma unroll
  for (int mm = 0; mm < 8; ++mm) {
    int o = mm * 16 + s * 4;
    float4 dv = *(const float4*)(dr + o);
#pragma unroll
    for (int nn = 0; nn < 2; ++nn) {
      int t = wid * 32 + nn * 16 + ln15;
      f32x4 r;
      r[0] = acc[mm][nn][0] * dv.x;
      r[1] = acc[mm][nn][1] * dv.y;
      r[2] = acc[mm][nn][2] * dv.z;
      r[3] = acc[mm][nn][3] * dv.w;
      *(f32x4*)(ob + (size_t)t * COUT + o) = r;
    }
  }
}

// ---------------------------------------------------------------------------
extern "C" void kernel_launch(void* const* d_in, const int* in_sizes, int n_in,
                              void* d_out, int out_size, void* d_ws, size_t ws_size,
                              hipStream_t stream) {
  const float* x      = (const float*)d_in[0];  // (8,4096,512)
  const float* style  = (const float*)d_in[1];  // (8,512)
  const float* weight = (const float*)d_in[2];  // (1,512,512)
  const float* mod_w  = (const float*)d_in[3];  // (512,512)
  const float* mod_b  = (const float*)d_in[4];  // (512,)
  float* out = (float*)d_out;

  // ws: m[8*512] f32 (16KB) | demod[8*512] f32 (16KB) | wimg 512KB
  float*  m_buf = (float*)d_ws;
  float*  demod = m_buf + B_ * CIN;
  __bf16* wimg  = (__bf16*)((char*)d_ws + 2 * B_ * CIN * sizeof(float));

  // allow 128 KB dynamic LDS (host-side attribute; not a stream op)
  hipFuncSetAttribute((const void*)k_gemm,
                      hipFuncAttributeMaxDynamicSharedMemorySize, 131072);

  k_stylefc<<<dim3((B_ * CIN) / 4), dim3(256), 0, stream>>>(style, mod_w, mod_b, m_buf);
  k_wprep<<<dim3(COUT), dim3(256), 0, stream>>>(weight, m_buf, wimg, demod);
  k_gemm<<<dim3(256), dim3(1024), 131072, stream>>>(x, wimg, m_buf, demod, out);
}